// Round 9
// baseline (282.301 us; speedup 1.0000x reference)
//
#include <hip/hip_runtime.h>
#include <math.h>

#define BATCH 4096
#define T 128
#define HOR 24

#define LOG2E 1.44269504088896f
#define C2    2.88539008177793f   // 2*log2(e)

typedef _Float16 half2_t __attribute__((ext_vector_type(2)));
typedef _Float16 half8   __attribute__((ext_vector_type(8)));
typedef float f2  __attribute__((ext_vector_type(2)));
typedef float f4v __attribute__((ext_vector_type(4)));

__device__ __forceinline__ float fexp2(float x){ return __builtin_amdgcn_exp2f(x); }
__device__ __forceinline__ float frcp(float x){ return __builtin_amdgcn_rcpf(x); }
__device__ __forceinline__ float fsig(float x){ return frcp(1.0f + fexp2(-LOG2E*x)); }
__device__ __forceinline__ float ftanh(float x){ return fmaf(-2.0f, frcp(1.0f + fexp2(C2*x)), 1.0f); }
__device__ __forceinline__ half2_t bch(unsigned u){ return __builtin_bit_cast(half2_t,u); }
__device__ __forceinline__ unsigned pk2(float a,float b){ return __builtin_bit_cast(unsigned, __builtin_amdgcn_cvt_pkrtz(a,b)); }
// RNE f32-pair -> packed f16 (for exp2 values: keep full fp16 accuracy, no RTZ bias)
__device__ __forceinline__ unsigned pk2rne(float a,float b){
  half2_t h; h.x = (_Float16)a; h.y = (_Float16)b;
  return __builtin_bit_cast(unsigned, h);
}
__device__ __forceinline__ float fdot2f(half2_t a, half2_t b, float c){
#if __has_builtin(__builtin_amdgcn_fdot2)
  return __builtin_amdgcn_fdot2(a,b,c,false);
#else
  return fmaf((float)a.x,(float)b.x, fmaf((float)a.y,(float)b.y,c));
#endif
}
__device__ __forceinline__ f2 pkfma(f2 a, f2 b, f2 c){ return __builtin_elementwise_fma(a,b,c); }

template <int CTRL, int RMASK>
__device__ __forceinline__ float dpp_add(float v) {
  int s = __builtin_amdgcn_update_dpp(0, __builtin_bit_cast(int, v), CTRL, RMASK, 0xf, true);
  return v + __builtin_bit_cast(float, s);
}
__device__ __forceinline__ float wavesum_dpp(float v) {
  v = dpp_add<0x111, 0xf>(v);
  v = dpp_add<0x112, 0xf>(v);
  v = dpp_add<0x114, 0xf>(v);
  v = dpp_add<0x118, 0xf>(v);
  v = dpp_add<0x142, 0xa>(v);
  v = dpp_add<0x143, 0xc>(v);
  return v;                     // total in lane 63
}
__device__ __forceinline__ float rdl63(float v){
  return __builtin_bit_cast(float, __builtin_amdgcn_readlane(__builtin_bit_cast(int, v), 63));
}

// Barrier that does NOT drain vmcnt: LDS producer/consumer ordering only.
#define WG_BARRIER_LDS() do {                                   \
    asm volatile("s_waitcnt lgkmcnt(0)" ::: "memory");          \
    __builtin_amdgcn_s_barrier();                               \
  } while (0)

__device__ __forceinline__ void gru_mv(const _Float16* hrow,
    const unsigned* wr_r, const unsigned* wr_z, const unsigned* wr_n,
    float& ar0, float& ar1, float& az0, float& az1, float& an0, float& an1)
{
  const uint4* hq = (const uint4*)hrow;
  #pragma unroll
  for (int q = 0; q < 8; ++q) {
    uint4 hv = hq[q];
    ar0 = fdot2f(bch(hv.x), bch(wr_r[4*q+0]), ar0);
    az0 = fdot2f(bch(hv.x), bch(wr_z[4*q+0]), az0);
    an0 = fdot2f(bch(hv.x), bch(wr_n[4*q+0]), an0);
    ar1 = fdot2f(bch(hv.y), bch(wr_r[4*q+1]), ar1);
    az1 = fdot2f(bch(hv.y), bch(wr_z[4*q+1]), az1);
    an1 = fdot2f(bch(hv.y), bch(wr_n[4*q+1]), an1);
    ar0 = fdot2f(bch(hv.z), bch(wr_r[4*q+2]), ar0);
    az0 = fdot2f(bch(hv.z), bch(wr_z[4*q+2]), az0);
    an0 = fdot2f(bch(hv.z), bch(wr_n[4*q+2]), an0);
    ar1 = fdot2f(bch(hv.w), bch(wr_r[4*q+3]), ar1);
    az1 = fdot2f(bch(hv.w), bch(wr_z[4*q+3]), az1);
    an1 = fdot2f(bch(hv.w), bch(wr_n[4*q+3]), an1);
  }
}

__device__ __forceinline__ float proj_dot(const _Float16* base, const unsigned* udr)
{
  float acc = 0.f;
  const uint4* hb = (const uint4*)base;
  #pragma unroll
  for (int q = 0; q < 4; ++q) {
    uint4 hv = hb[q];
    acc = fdot2f(bch(hv.x), bch(udr[4*q+0]), acc);
    acc = fdot2f(bch(hv.y), bch(udr[4*q+1]), acc);
    acc = fdot2f(bch(hv.z), bch(udr[4*q+2]), acc);
    acc = fdot2f(bch(hv.w), bch(udr[4*q+3]), acc);
  }
  return acc;
}

__device__ __forceinline__ half8 cvt8(f4v a, f4v b){
  half8 h;
  h[0]=(_Float16)a.x; h[1]=(_Float16)a.y; h[2]=(_Float16)a.z; h[3]=(_Float16)a.w;
  h[4]=(_Float16)b.x; h[5]=(_Float16)b.y; h[6]=(_Float16)b.z; h[7]=(_Float16)b.w;
  return h;
}

// 4-term grouped sigma-sum: returns acc + sum_k v_k / A_k with ONE rcp.
__device__ __forceinline__ float grp4(float acc, f4v ed,
                                      half2_t ha, half2_t hb,
                                      float v0, float v1, float v2, float v3)
{
  float a0 = fmaf(ed.x, (float)ha.x, 1.0f);
  float a1 = fmaf(ed.y, (float)ha.y, 1.0f);
  float a2 = fmaf(ed.z, (float)hb.x, 1.0f);
  float a3 = fmaf(ed.w, (float)hb.y, 1.0f);
  float d01 = a0 * a1;
  float d23 = a2 * a3;
  float n01 = fmaf(v0, a1, v1 * a0);
  float n23 = fmaf(v2, a3, v3 * a2);
  float nc  = fmaf(n01, d23, n23 * d01);
  return fmaf(nc, frcp(d01 * d23), acc);
}

// ============ Kernel A: encoder — 8-wave m-split x K-split =================
// R23: grid is structurally 256 column-groups (4096/16) = 1 block/CU; the
// 4-wave m-split left 1 wave/SIMD with the whole chain latency-exposed
// (step ~2800cy vs ~600cy issue; R17: 2 contexts/SIMD recover 1.63x even with
// 2x dead work). Split 8 ways: wave (M,kp) = units [16M,16M+16) x h-half
// [32kp,32kp+32) -> ONE K=32 MFMA per gate. Partials exchanged via LDS
// (lane-aligned slots, conflict-free); kp=0 waves combine + gates + write h
// (trans stays 8/wave over 4 SIMDs); kp=1 waves combine + finish Eh. Two
// lgkm-only barriers/step, single He buffer (reads/writes barrier-separated).
// 8 waves = 2/SIMD: every stall source now has a co-resident wave to hide it.
__global__ __launch_bounds__(512, 2)
void darnn_enc(const float* __restrict__ x,
               const float* __restrict__ W_ih_e, const float* __restrict__ W_hh_e,
               const float* __restrict__ b_ih_e, const float* __restrict__ b_hh_e,
               const float* __restrict__ U_d, const float* __restrict__ W_out,
               unsigned* __restrict__ hpG, float* __restrict__ hTG)
{
  const int tid = threadIdx.x;
  const int w   = tid >> 6;      // wave 0..7
  const int M   = w & 3;         // unit block: units [16M, 16M+16)
  const int kp  = w >> 2;        // k-half: h[32kp, 32kp+32)
  const int l   = tid & 63;
  const int c   = l & 15;        // MFMA column = element slot
  const int q   = l >> 4;        // quad
  const int e0  = blockIdx.x * 16;
  const int m0  = 16*M + 4*q;    // gate-wave's 4 hidden units

  __shared__ __align__(16) _Float16 He[16*72];   // h[e][k], pad 72 (single buf)
  __shared__ __align__(16) unsigned xw[16*65];   // x fp16-pairs [e][65]
  __shared__ __align__(16) uint4 Pg[4][3][64];   // gate partials (from kp=1)
  __shared__ __align__(16) uint4 Pe[3][64];      // Eh/hw partials (from kp=0)

  // ---- stage x + zero He (cooperative, 512 threads) ----
  for (int idx = tid; idx < 16*64; idx += 512) {
    int e = idx >> 6, j = idx & 63;
    f2 g = ((const f2*)(x + (size_t)(e0+e)*T))[j];
    xw[e*65 + j] = pk2(g.x, g.y);
  }
  for (int idx = tid; idx < 576; idx += 512) ((unsigned*)He)[idx] = 0;

  // ---- A-frags: this wave's W_hh rows (r/z/n), k-half kp -> 1 half8 each ----
  half8 Ar, Az, An;
  {
    const f4v* pr = (const f4v*)(W_hh_e + (size_t)(16*M + c)*64       + 32*kp + 8*q);
    const f4v* pz = (const f4v*)(W_hh_e + (size_t)(64 + 16*M + c)*64  + 32*kp + 8*q);
    const f4v* pn = (const f4v*)(W_hh_e + (size_t)(128 + 16*M + c)*64 + 32*kp + 8*q);
    Ar = cvt8(pr[0], pr[1]);
    Az = cvt8(pz[0], pz[1]);
    An = cvt8(pn[0], pn[1]);
  }
  // ---- Eh A-frags: waves (0,kp)/(1,kp) -> U_d rows 0-15/16-31 (xC2);
  //      wave (2,kp) c==0 -> W_out ctx row; wave 3 none ----
  half8 AX = (half8){0,0,0,0,0,0,0,0};
  half8 AW = (half8){0,0,0,0,0,0,0,0};
  if (M < 2) {
    const f4v* p = (const f4v*)(U_d + (size_t)(16*M + c)*64 + 32*kp + 8*q);
    AX = cvt8(p[0] * C2, p[1] * C2);
  } else if (M == 2 && c == 0) {
    const f4v* p = (const f4v*)(W_out + 64 + 32*kp + 8*q);
    AW = cvt8(p[0], p[1]);
  }
  // ---- per-lane gate params for units m0..m0+3 (used by kp=0 only) ----
  f4v wih0 = *(const f4v*)(W_ih_e + m0);
  f4v wih1 = *(const f4v*)(W_ih_e + 64 + m0);
  f4v wih2 = *(const f4v*)(W_ih_e + 128 + m0);
  f4v bb0  = *(const f4v*)(b_ih_e + m0)      + *(const f4v*)(b_hh_e + m0);
  f4v bb1  = *(const f4v*)(b_ih_e + 64 + m0) + *(const f4v*)(b_hh_e + 64 + m0);
  f4v bi2  = *(const f4v*)(b_ih_e + 128 + m0);
  f4v bh2  = *(const f4v*)(b_hh_e + 128 + m0);
  f4v hreg = {0,0,0,0};
  const f4v z4 = {0,0,0,0};
  unsigned* hpB = hpG + (size_t)(e0 + c) * 2176;

  __syncthreads();   // staging visible

  // ---- 128 steps: 2 lgkm-barriers/step, partial-exchange through LDS ----
  #pragma unroll 1
  for (int t = 0; t < T; ++t) {
    // read this wave's K-half of h_{t-1} (B-frag, one uint4)
    half8 B = __builtin_bit_cast(half8, *(const uint4*)(He + c*72 + 32*kp + 8*q));
    f4v pgr = __builtin_amdgcn_mfma_f32_16x16x32_f16(Ar, B, z4, 0,0,0);
    f4v pgz = __builtin_amdgcn_mfma_f32_16x16x32_f16(Az, B, z4, 0,0,0);
    f4v pgn = __builtin_amdgcn_mfma_f32_16x16x32_f16(An, B, z4, 0,0,0);
    f4v peh = z4, pw = z4;
    if (M < 2)  peh = __builtin_amdgcn_mfma_f32_16x16x32_f16(AX, B, z4, 0,0,0);
    if (M == 2) pw  = __builtin_amdgcn_mfma_f32_16x16x32_f16(AW, B, z4, 0,0,0);
    // exchange: kp=1 publishes gate partials; kp=0 publishes Eh/hw partials
    if (kp == 1) {
      Pg[M][0][l] = __builtin_bit_cast(uint4, pgr);
      Pg[M][1][l] = __builtin_bit_cast(uint4, pgz);
      Pg[M][2][l] = __builtin_bit_cast(uint4, pgn);
    } else {
      if (M < 2)  Pe[M][l] = __builtin_bit_cast(uint4, peh);
      if (M == 2) Pe[2][l] = __builtin_bit_cast(uint4, pw);
    }
    WG_BARRIER_LDS();                       // partials + h-reads complete
    if (kp == 0) {
      // gates: own K-half + partner's
      f4v gr = pgr + __builtin_bit_cast(f4v, Pg[M][0][l]);
      f4v gz = pgz + __builtin_bit_cast(f4v, Pg[M][1][l]);
      f4v gn = pgn + __builtin_bit_cast(f4v, Pg[M][2][l]);
      float xc = (float)((const _Float16*)xw)[c*130 + t];
      f4v hn;
      #pragma unroll
      for (int i = 0; i < 4; ++i) {
        float r  = fsig(fmaf(xc, wih0[i], bb0[i]) + gr[i]);
        float zf = fsig(fmaf(xc, wih1[i], bb1[i]) + gz[i]);
        float n  = ftanh(fmaf(xc, wih2[i], bi2[i]) + r*(gn[i] + bh2[i]));
        float h  = fmaf(zf, hreg[i] - n, n);
        hreg[i] = h;
        hn[i] = h;
      }
      uint2 wv; wv.x = pk2(hn[0], hn[1]); wv.y = pk2(hn[2], hn[3]);
      *(uint2*)(He + c*72 + m0) = wv;
    } else if (t > 0) {
      // Eh/hw finishing for h_{t-1} (stored at t-1), own half + partner's
      if (M < 2) {
        f4v cu = peh + __builtin_bit_cast(f4v, Pe[M][l]);
        unsigned* hpE = hpB + (t-1)*17 + 8*M;
        float x0 = fexp2(fminf(cu[0], 15.5f));
        float x1 = fexp2(fminf(cu[1], 15.5f));
        float x2 = fexp2(fminf(cu[2], 15.5f));
        float x3 = fexp2(fminf(cu[3], 15.5f));
        hpE[2*q]   = pk2rne(x0, x1);
        hpE[2*q+1] = pk2rne(x2, x3);
      } else if (M == 2) {
        f4v cw = pw + __builtin_bit_cast(f4v, Pe[2][l]);
        if (q == 0) ((float*)(hpB + (t-1)*17))[16] = cw[0];
      }
    }
    WG_BARRIER_LDS();                       // h writes complete
  }
  // ---- epilogue: Eh/hw for t=127 from He (= h_127) ----
  {
    half8 B = __builtin_bit_cast(half8, *(const uint4*)(He + c*72 + 32*kp + 8*q));
    f4v peh = z4, pw = z4;
    if (M < 2)  peh = __builtin_amdgcn_mfma_f32_16x16x32_f16(AX, B, z4, 0,0,0);
    if (M == 2) pw  = __builtin_amdgcn_mfma_f32_16x16x32_f16(AW, B, z4, 0,0,0);
    if (kp == 0) {
      if (M < 2)  Pe[M][l] = __builtin_bit_cast(uint4, peh);
      if (M == 2) Pe[2][l] = __builtin_bit_cast(uint4, pw);
    }
    WG_BARRIER_LDS();
    if (kp == 1) {
      if (M < 2) {
        f4v cu = peh + __builtin_bit_cast(f4v, Pe[M][l]);
        unsigned* hpE = hpB + 127*17 + 8*M;
        float x0 = fexp2(fminf(cu[0], 15.5f));
        float x1 = fexp2(fminf(cu[1], 15.5f));
        float x2 = fexp2(fminf(cu[2], 15.5f));
        float x3 = fexp2(fminf(cu[3], 15.5f));
        hpE[2*q]   = pk2rne(x0, x1);
        hpE[2*q+1] = pk2rne(x2, x3);
      } else if (M == 2) {
        f4v cw = pw + __builtin_bit_cast(f4v, Pe[2][l]);
        if (q == 0) ((float*)(hpB + 127*17))[16] = cw[0];
      }
    }
  }
  // ---- h_T (fp32): gate-waves own hreg ----
  if (kp == 0) {
    #pragma unroll
    for (int i = 0; i < 4; ++i)
      hTG[(size_t)(e0 + c)*64 + m0 + i] = hreg[i];
  }
}

// ============ Kernel B: decoder — R22 (proven 116 us), unchanged ===========
__global__ __launch_bounds__(128, 2)
void darnn_dec(const float* __restrict__ W_init, const float* __restrict__ b_init,
               const float* __restrict__ W_ih_d, const float* __restrict__ W_hh_d,
               const float* __restrict__ b_ih_d, const float* __restrict__ b_hh_d,
               const float* __restrict__ W_d, const float* __restrict__ v_d,
               const float* __restrict__ W_out, const float* __restrict__ b_out,
               const float* __restrict__ y0,
               const unsigned* __restrict__ hpG, const float* __restrict__ hTG,
               float* __restrict__ out)
{
  const int tid = threadIdx.x;
  const int wid = tid >> 6;
  const int l   = tid & 63;
  const int bA  = 4*blockIdx.x + 2*wid;
  const int bB  = bA + 1;
  const int a    = l & 31;
  const int half = l >> 5;

  __shared__ __align__(16) unsigned char smem[36928];
  unsigned char* wbp = smem + wid*18464;
  unsigned* hpA   = (unsigned*)wbp;                  // Eh fp16 pairs (+hw f32)
  unsigned* hpB   = (unsigned*)(wbp + 8704);
  _Float16* ringA = (_Float16*)(wbp + 17408);
  _Float16* ringB = (_Float16*)(wbp + 17536);
  float*    dpA   = (float*)(wbp + 17664);           // Edp = exp2(C2*W_d.d)
  float*    dpB   = (float*)(wbp + 17792);
  float*    hTA   = (float*)(wbp + 17920);
  float*    hTB   = (float*)(wbp + 18176);

  {
    const uint4* sA = (const uint4*)(hpG + (size_t)bA * 2176);
    const uint4* sB = (const uint4*)(hpG + (size_t)bB * 2176);
    #pragma unroll
    for (int it = 0; it < 8; ++it) {
      ((uint4*)hpA)[it*64 + l] = sA[it*64 + l];
      ((uint4*)hpB)[it*64 + l] = sB[it*64 + l];
    }
    const unsigned* rA = hpG + (size_t)bA*2176 + 2048;
    const unsigned* rB = hpG + (size_t)bB*2176 + 2048;
    hpA[2048 + l] = rA[l];      hpA[2112 + l] = rA[64 + l];
    hpB[2048 + l] = rB[l];      hpB[2112 + l] = rB[64 + l];
  }
  hTA[l] = hTG[(size_t)bA*64 + l];
  hTB[l] = hTG[(size_t)bB*64 + l];

  unsigned wr_r[32], wr_z[32], wr_n[32];
  {
    const f4v* wp = (const f4v*)W_hh_d;
    #pragma unroll
    for (int k = 0; k < 16; ++k) {
      f4v vr = wp[l*16 + k];
      f4v vz = wp[(64 + l)*16 + k];
      f4v vn = wp[(128 + l)*16 + k];
      wr_r[2*k] = pk2(vr.x, vr.y); wr_r[2*k+1] = pk2(vr.z, vr.w);
      wr_z[2*k] = pk2(vz.x, vz.y); wr_z[2*k+1] = pk2(vz.z, vz.w);
      wr_n[2*k] = pk2(vn.x, vn.y); wr_n[2*k+1] = pk2(vn.z, vn.w);
    }
  }
  float wih0 = W_ih_d[l], wih1 = W_ih_d[64+l], wih2 = W_ih_d[128+l];
  float bb0  = b_ih_d[l] + b_hh_d[l];
  float bb1  = b_ih_d[64+l] + b_hh_d[64+l];
  float bih2 = b_ih_d[128+l], bhh2 = b_hh_d[128+l];
  unsigned udr[16];
  {
    const f2* up = (const f2*)(W_d + a*64 + half*32);
    #pragma unroll
    for (int k = 0; k < 16; ++k) { f2 f = up[k]; udr[k] = pk2(f.x, f.y); }
  }
  float dprevA, dprevB;
  {
    const f4v* wi = (const f4v*)(W_init + l*64);
    const f4v* ga = (const f4v*)hTA;
    const f4v* gb = (const f4v*)hTB;
    f2 aa0={0,0}, aa1={0,0}, ba0={0,0}, ba1={0,0};
    #pragma unroll
    for (int k = 0; k < 16; ++k) {
      f4v wv = wi[k];
      f4v va = ga[k], vb = gb[k];
      aa0 = pkfma(wv.xy, va.xy, aa0);
      aa1 = pkfma(wv.zw, va.zw, aa1);
      ba0 = pkfma(wv.xy, vb.xy, ba0);
      ba1 = pkfma(wv.zw, vb.zw, ba1);
    }
    float bi = b_init[l];
    dprevA = bi + (aa0.x + aa0.y) + (aa1.x + aa1.y);
    dprevB = bi + (ba0.x + ba0.y) + (ba1.x + ba1.y);
  }
  float wout1 = W_out[l];
  float hw0A = __builtin_bit_cast(float, hpA[l*17 + 16]);
  float hw1A = __builtin_bit_cast(float, hpA[(64 + l)*17 + 16]);
  float hw0B = __builtin_bit_cast(float, hpB[l*17 + 16]);
  float hw1B = __builtin_bit_cast(float, hpB[(64 + l)*17 + 16]);
  float oprevA = y0[0], oprevB = y0[0];
  float bo = b_out[0];
  float c1;
  {
    float sv = v_d[a];
    sv += __shfl_xor(sv, 16); sv += __shfl_xor(sv, 8);
    sv += __shfl_xor(sv, 4);  sv += __shfl_xor(sv, 2); sv += __shfl_xor(sv, 1);
    c1 = LOG2E * sv;
  }
  ringA[l] = (_Float16)dprevA;
  ringB[l] = (_Float16)dprevB;

  const unsigned* hprA0 = hpA + l*17;
  const unsigned* hprA1 = hpA + (64 + l)*17;
  const unsigned* hprB0 = hpB + l*17;
  const unsigned* hprB1 = hpB + (64 + l)*17;

  #pragma unroll 1
  for (int s = 0; s < HOR; ++s) {
    float ar0A=0,ar1A=0,az0A=0,az1A=0,an0A=0,an1A=0;
    float ar0B=0,ar1B=0,az0B=0,az1B=0,an0B=0,an1B=0;
    gru_mv(ringA, wr_r, wr_z, wr_n, ar0A,ar1A,az0A,az1A,an0A,an1A);
    gru_mv(ringB, wr_r, wr_z, wr_n, ar0B,ar1B,az0B,az1B,an0B,an1B);
    float rA = fsig(fmaf(oprevA, wih0, bb0) + ar0A + ar1A);
    float zA = fsig(fmaf(oprevA, wih1, bb1) + az0A + az1A);
    float nA = ftanh(fmaf(oprevA, wih2, bih2) + rA * (an0A + an1A + bhh2));
    float dnewA = fmaf(zA, dprevA - nA, nA);
    float rB = fsig(fmaf(oprevB, wih0, bb0) + ar0B + ar1B);
    float zB = fsig(fmaf(oprevB, wih1, bb1) + az0B + az1B);
    float nB = ftanh(fmaf(oprevB, wih2, bih2) + rB * (an0B + an1B + bhh2));
    float dnewB = fmaf(zB, dprevB - nB, nB);
    dprevA = dnewA; dprevB = dnewB;
    ringA[l] = (_Float16)dnewA;
    ringB[l] = (_Float16)dnewB;
    {
      float accA = proj_dot(ringA + half*32, udr);
      float accB = proj_dot(ringB + half*32, udr);
      accA += __shfl_xor(accA, 32);
      accB += __shfl_xor(accB, 32);
      if (l < 32) {
        dpA[l] = fexp2(fminf(C2 * accA, 15.5f));
        dpB[l] = fexp2(fminf(C2 * accB, 15.5f));
      }
    }
    float rs0A = 0.f, rs1A = 0.f, rs0B = 0.f, rs1B = 0.f;
    #pragma unroll
    for (int j2 = 0; j2 < 8; ++j2) {
      f4v edA = *(const f4v*)&dpA[4*j2];
      f4v edB = *(const f4v*)&dpB[4*j2];
      half2_t haA0 = bch(hprA0[2*j2]), hbA0 = bch(hprA0[2*j2+1]);
      half2_t haA1 = bch(hprA1[2*j2]), hbA1 = bch(hprA1[2*j2+1]);
      half2_t haB0 = bch(hprB0[2*j2]), hbB0 = bch(hprB0[2*j2+1]);
      half2_t haB1 = bch(hprB1[2*j2]), hbB1 = bch(hprB1[2*j2+1]);
      float v0 = v_d[4*j2], v1 = v_d[4*j2+1], v2 = v_d[4*j2+2], v3 = v_d[4*j2+3];
      rs0A = grp4(rs0A, edA, haA0, hbA0, v0, v1, v2, v3);
      rs0B = grp4(rs0B, edB, haB0, hbB0, v0, v1, v2, v3);
      rs1A = grp4(rs1A, edA, haA1, hbA1, v0, v1, v2, v3);
      rs1B = grp4(rs1B, edB, haB1, hbB1, v0, v1, v2, v3);
    }
    float e0A = fexp2(fmaf(-C2, rs0A, c1));
    float e1A = fexp2(fmaf(-C2, rs1A, c1));
    float e0B = fexp2(fmaf(-C2, rs0B, c1));
    float e1B = fexp2(fmaf(-C2, rs1B, c1));
    float P0A = rdl63(wavesum_dpp(e0A + e1A));
    float P1A = rdl63(wavesum_dpp(fmaf(e0A, hw0A, e1A * hw1A)));
    float P2A = rdl63(wavesum_dpp(wout1 * dnewA));
    float P0B = rdl63(wavesum_dpp(e0B + e1B));
    float P1B = rdl63(wavesum_dpp(fmaf(e0B, hw0B, e1B * hw1B)));
    float P2B = rdl63(wavesum_dpp(wout1 * dnewB));
    float oA = fmaf(P1A, frcp(P0A), P2A + bo);
    float oB = fmaf(P1B, frcp(P0B), P2B + bo);
    if (l == 0) {
      out[(size_t)bA * HOR + s] = oA;
      out[(size_t)bB * HOR + s] = oB;
    }
    oprevA = oA; oprevB = oB;
  }
}

extern "C" void kernel_launch(void* const* d_in, const int* in_sizes, int n_in,
                              void* d_out, int out_size, void* d_ws, size_t ws_size,
                              hipStream_t stream) {
  const float* x      = (const float*)d_in[0];
  const float* W_ih_e = (const float*)d_in[1];
  const float* W_hh_e = (const float*)d_in[2];
  const float* b_ih_e = (const float*)d_in[3];
  const float* b_hh_e = (const float*)d_in[4];
  // d_in[5..8] = W_e, U_e, b_e, v_e : dead (softmax over size-1 axis == 1)
  const float* W_init = (const float*)d_in[9];
  const float* b_init = (const float*)d_in[10];
  const float* W_ih_d = (const float*)d_in[11];
  const float* W_hh_d = (const float*)d_in[12];
  const float* b_ih_d = (const float*)d_in[13];
  const float* b_hh_d = (const float*)d_in[14];
  const float* W_d    = (const float*)d_in[15];
  const float* U_d    = (const float*)d_in[16];
  const float* v_d    = (const float*)d_in[17];
  const float* W_out  = (const float*)d_in[18];
  const float* b_out  = (const float*)d_in[19];
  const float* y0     = (const float*)d_in[20];
  float* outp = (float*)d_out;

  unsigned* hpG = (unsigned*)d_ws;
  float*    hTG = (float*)((char*)d_ws + (size_t)BATCH * 2176 * 4);

  darnn_enc<<<BATCH/16, 512, 0, stream>>>(x, W_ih_e, W_hh_e, b_ih_e, b_hh_e,
      U_d, W_out, hpG, hTG);
  darnn_dec<<<BATCH/4, 128, 0, stream>>>(W_init, b_init, W_ih_d, W_hh_d,
      b_ih_d, b_hh_d, W_d, v_d, W_out, b_out, y0, hpG, hTG, outp);
}

// Round 10
// 251.900 us; speedup vs baseline: 1.1207x; 1.1207x over previous
//
#include <hip/hip_runtime.h>
#include <math.h>

#define BATCH 4096
#define T 128
#define HOR 24

#define LOG2E 1.44269504088896f
#define C2    2.88539008177793f   // 2*log2(e)

typedef _Float16 half2_t __attribute__((ext_vector_type(2)));
typedef _Float16 half8   __attribute__((ext_vector_type(8)));
typedef float f2  __attribute__((ext_vector_type(2)));
typedef float f4v __attribute__((ext_vector_type(4)));

__device__ __forceinline__ float fexp2(float x){ return __builtin_amdgcn_exp2f(x); }
__device__ __forceinline__ float frcp(float x){ return __builtin_amdgcn_rcpf(x); }
__device__ __forceinline__ float fsig(float x){ return frcp(1.0f + fexp2(-LOG2E*x)); }
__device__ __forceinline__ float ftanh(float x){ return fmaf(-2.0f, frcp(1.0f + fexp2(C2*x)), 1.0f); }
__device__ __forceinline__ half2_t bch(unsigned u){ return __builtin_bit_cast(half2_t,u); }
__device__ __forceinline__ unsigned pk2(float a,float b){ return __builtin_bit_cast(unsigned, __builtin_amdgcn_cvt_pkrtz(a,b)); }
// RNE f32-pair -> packed f16 (for exp2 values: keep full fp16 accuracy, no RTZ bias)
__device__ __forceinline__ unsigned pk2rne(float a,float b){
  half2_t h; h.x = (_Float16)a; h.y = (_Float16)b;
  return __builtin_bit_cast(unsigned, h);
}
__device__ __forceinline__ float fdot2f(half2_t a, half2_t b, float c){
#if __has_builtin(__builtin_amdgcn_fdot2)
  return __builtin_amdgcn_fdot2(a,b,c,false);
#else
  return fmaf((float)a.x,(float)b.x, fmaf((float)a.y,(float)b.y,c));
#endif
}
__device__ __forceinline__ f2 pkfma(f2 a, f2 b, f2 c){ return __builtin_elementwise_fma(a,b,c); }

template <int CTRL, int RMASK>
__device__ __forceinline__ float dpp_add(float v) {
  int s = __builtin_amdgcn_update_dpp(0, __builtin_bit_cast(int, v), CTRL, RMASK, 0xf, true);
  return v + __builtin_bit_cast(float, s);
}
__device__ __forceinline__ float wavesum_dpp(float v) {
  v = dpp_add<0x111, 0xf>(v);
  v = dpp_add<0x112, 0xf>(v);
  v = dpp_add<0x114, 0xf>(v);
  v = dpp_add<0x118, 0xf>(v);
  v = dpp_add<0x142, 0xa>(v);
  v = dpp_add<0x143, 0xc>(v);
  return v;                     // total in lane 63
}
__device__ __forceinline__ float rdl63(float v){
  return __builtin_bit_cast(float, __builtin_amdgcn_readlane(__builtin_bit_cast(int, v), 63));
}

// Barrier that does NOT drain vmcnt: LDS producer/consumer ordering only.
#define WG_BARRIER_LDS() do {                                   \
    asm volatile("s_waitcnt lgkmcnt(0)" ::: "memory");          \
    __builtin_amdgcn_s_barrier();                               \
  } while (0)

__device__ __forceinline__ void gru_mv(const _Float16* hrow,
    const unsigned* wr_r, const unsigned* wr_z, const unsigned* wr_n,
    float& ar0, float& ar1, float& az0, float& az1, float& an0, float& an1)
{
  const uint4* hq = (const uint4*)hrow;
  #pragma unroll
  for (int q = 0; q < 8; ++q) {
    uint4 hv = hq[q];
    ar0 = fdot2f(bch(hv.x), bch(wr_r[4*q+0]), ar0);
    az0 = fdot2f(bch(hv.x), bch(wr_z[4*q+0]), az0);
    an0 = fdot2f(bch(hv.x), bch(wr_n[4*q+0]), an0);
    ar1 = fdot2f(bch(hv.y), bch(wr_r[4*q+1]), ar1);
    az1 = fdot2f(bch(hv.y), bch(wr_z[4*q+1]), az1);
    an1 = fdot2f(bch(hv.y), bch(wr_n[4*q+1]), an1);
    ar0 = fdot2f(bch(hv.z), bch(wr_r[4*q+2]), ar0);
    az0 = fdot2f(bch(hv.z), bch(wr_z[4*q+2]), az0);
    an0 = fdot2f(bch(hv.z), bch(wr_n[4*q+2]), an0);
    ar1 = fdot2f(bch(hv.w), bch(wr_r[4*q+3]), ar1);
    az1 = fdot2f(bch(hv.w), bch(wr_z[4*q+3]), az1);
    an1 = fdot2f(bch(hv.w), bch(wr_n[4*q+3]), an1);
  }
}

__device__ __forceinline__ float proj_dot(const _Float16* base, const unsigned* udr)
{
  float acc = 0.f;
  const uint4* hb = (const uint4*)base;
  #pragma unroll
  for (int q = 0; q < 4; ++q) {
    uint4 hv = hb[q];
    acc = fdot2f(bch(hv.x), bch(udr[4*q+0]), acc);
    acc = fdot2f(bch(hv.y), bch(udr[4*q+1]), acc);
    acc = fdot2f(bch(hv.z), bch(udr[4*q+2]), acc);
    acc = fdot2f(bch(hv.w), bch(udr[4*q+3]), acc);
  }
  return acc;
}

__device__ __forceinline__ half8 cvt8(f4v a, f4v b){
  half8 h;
  h[0]=(_Float16)a.x; h[1]=(_Float16)a.y; h[2]=(_Float16)a.z; h[3]=(_Float16)a.w;
  h[4]=(_Float16)b.x; h[5]=(_Float16)b.y; h[6]=(_Float16)b.z; h[7]=(_Float16)b.w;
  return h;
}

// 4-term grouped sigma-sum: returns acc + sum_k v_k / A_k with ONE rcp.
__device__ __forceinline__ float grp4(float acc, f4v ed,
                                      half2_t ha, half2_t hb,
                                      float v0, float v1, float v2, float v3)
{
  float a0 = fmaf(ed.x, (float)ha.x, 1.0f);
  float a1 = fmaf(ed.y, (float)ha.y, 1.0f);
  float a2 = fmaf(ed.z, (float)hb.x, 1.0f);
  float a3 = fmaf(ed.w, (float)hb.y, 1.0f);
  float d01 = a0 * a1;
  float d23 = a2 * a3;
  float n01 = fmaf(v0, a1, v1 * a0);
  float n23 = fmaf(v2, a3, v3 * a2);
  float nc  = fmaf(n01, d23, n23 * d01);
  return fmaf(nc, frcp(d01 * d23), acc);
}

// ============ FUSED kernel: R15 encoder + R22 decoder, Eh stays in LDS =====
// R24: the enc->dec seam cost 35.6 MB of Eh through global (dec FETCH 18.3MB
// re-read; hpG > L2 aggregate) + launch gap + enc scattered stores. All 16
// elems a block encodes are the elems 8 dec-waves decode: fuse. Phase 1:
// waves 0-3 = R15 encoder verbatim, Eh/hw -> LDS EhS[16][2177] (odd strides:
// enc writes lane=elem stride 2177, dec reads lane=timestep stride 17 -> both
// conflict-free); waves 4-7 just match barriers. Phase 2: all 8 waves = R22
// decoder body, 2 elems/wave (same 8 waves/CU as R22), Eh/hT read from LDS.
// LDS total 156,288 B (<160 KiB HW cap; 128-160KB/WG plain-HIP precedent).
// Arithmetic bit-identical to R22.
__global__ __launch_bounds__(512, 2)
void darnn_fused(const float* __restrict__ x,
                 const float* __restrict__ W_ih_e, const float* __restrict__ W_hh_e,
                 const float* __restrict__ b_ih_e, const float* __restrict__ b_hh_e,
                 const float* __restrict__ U_d, const float* __restrict__ W_out,
                 const float* __restrict__ W_init, const float* __restrict__ b_init,
                 const float* __restrict__ W_ih_d, const float* __restrict__ W_hh_d,
                 const float* __restrict__ b_ih_d, const float* __restrict__ b_hh_d,
                 const float* __restrict__ W_d, const float* __restrict__ v_d,
                 const float* __restrict__ b_out, const float* __restrict__ y0,
                 float* __restrict__ out)
{
  const int tid = threadIdx.x;
  const int w   = tid >> 6;      // 0..7
  const int l   = tid & 63;
  const int c   = l & 15;        // enc: MFMA column = element slot
  const int q   = l >> 4;        // quad
  const int e0  = blockIdx.x * 16;

  __shared__ __align__(16) unsigned EhS[16*2177];   // Eh fp16 pairs + hw f32, per elem
  __shared__ __align__(16) _Float16 He[2][16*72];   // ping-pong h[e][k], pad 72
  __shared__ __align__(16) unsigned xw[16*65];      // x fp16-pairs [e][65]
  __shared__ __align__(16) float    hTS[16*64];     // h_T per elem
  __shared__ __align__(16) unsigned decScr[8*128];  // per-wave dec scratch

  // ---- stage x + zero He[0] (cooperative, all 512 threads) ----
  for (int idx = tid; idx < 16*64; idx += 512) {
    int e = idx >> 6, j = idx & 63;
    f2 g = ((const f2*)(x + (size_t)(e0+e)*T))[j];
    xw[e*65 + j] = pk2(g.x, g.y);
  }
  for (int idx = tid; idx < 576; idx += 512) ((unsigned*)He[0])[idx] = 0;

  // ---- enc setup (mw = w&3 keeps every load in-bounds for waves 4-7) ----
  const int mw = w & 3;
  const int m0 = 16*mw + 4*q;
  half8 Ar[2], Az[2], An[2];
  #pragma unroll
  for (int kap = 0; kap < 2; ++kap) {
    const f4v* pr = (const f4v*)(W_hh_e + (size_t)(16*mw + c)*64       + 32*kap + 8*q);
    const f4v* pz = (const f4v*)(W_hh_e + (size_t)(64 + 16*mw + c)*64  + 32*kap + 8*q);
    const f4v* pn = (const f4v*)(W_hh_e + (size_t)(128 + 16*mw + c)*64 + 32*kap + 8*q);
    Ar[kap] = cvt8(pr[0], pr[1]);
    Az[kap] = cvt8(pz[0], pz[1]);
    An[kap] = cvt8(pn[0], pn[1]);
  }
  half8 AX[2] = {{0,0,0,0,0,0,0,0},{0,0,0,0,0,0,0,0}};
  if (mw < 2) {
    #pragma unroll
    for (int kap = 0; kap < 2; ++kap) {
      const f4v* p = (const f4v*)(U_d + (size_t)(16*mw + c)*64 + 32*kap + 8*q);
      AX[kap] = cvt8(p[0] * C2, p[1] * C2);
    }
  } else if (mw == 2 && c == 0) {
    #pragma unroll
    for (int kap = 0; kap < 2; ++kap) {
      const f4v* p = (const f4v*)(W_out + 64 + 32*kap + 8*q);
      AX[kap] = cvt8(p[0], p[1]);
    }
  }
  f4v wih0e = *(const f4v*)(W_ih_e + m0);
  f4v wih1e = *(const f4v*)(W_ih_e + 64 + m0);
  f4v wih2e = *(const f4v*)(W_ih_e + 128 + m0);
  f4v bb0e  = *(const f4v*)(b_ih_e + m0)      + *(const f4v*)(b_hh_e + m0);
  f4v bb1e  = *(const f4v*)(b_ih_e + 64 + m0) + *(const f4v*)(b_hh_e + 64 + m0);
  f4v bi2e  = *(const f4v*)(b_ih_e + 128 + m0);
  f4v bh2e  = *(const f4v*)(b_hh_e + 128 + m0);
  f4v hreg = {0,0,0,0};
  const f4v z4 = {0,0,0,0};
  unsigned* ehB = EhS + c*2177;   // this lane's elem row (enc, waves 0-3)

  __syncthreads();

  // ---- PHASE 1: 128 enc steps (waves 0-3 work; 4-7 barrier-match) ----
  #pragma unroll 1
  for (int t = 0; t < T; ++t) {
    if (w < 4) {
      const _Float16* Hc = He[t & 1];
      half8 B0 = __builtin_bit_cast(half8, *(const uint4*)(Hc + c*72 + 8*q));
      half8 B1 = __builtin_bit_cast(half8, *(const uint4*)(Hc + c*72 + 32 + 8*q));
      if (t > 0) {           // Eh/hw for t-1 from h_{t-1} (= the B-frags)
        if (w < 2) {
          f4v cu = __builtin_amdgcn_mfma_f32_16x16x32_f16(AX[0], B0, z4, 0,0,0);
          cu     = __builtin_amdgcn_mfma_f32_16x16x32_f16(AX[1], B1, cu, 0,0,0);
          unsigned* hpE = ehB + (t-1)*17 + 8*w;
          float x0 = fexp2(fminf(cu[0], 15.5f));
          float x1 = fexp2(fminf(cu[1], 15.5f));
          float x2 = fexp2(fminf(cu[2], 15.5f));
          float x3 = fexp2(fminf(cu[3], 15.5f));
          hpE[2*q]   = pk2rne(x0, x1);
          hpE[2*q+1] = pk2rne(x2, x3);
        } else if (w == 2) {
          f4v cw = __builtin_amdgcn_mfma_f32_16x16x32_f16(AX[0], B0, z4, 0,0,0);
          cw     = __builtin_amdgcn_mfma_f32_16x16x32_f16(AX[1], B1, cw, 0,0,0);
          if (q == 0) ((float*)(ehB + (t-1)*17))[16] = cw[0];
        }
      }
      f4v gr = __builtin_amdgcn_mfma_f32_16x16x32_f16(Ar[0], B0, z4, 0,0,0);
      gr     = __builtin_amdgcn_mfma_f32_16x16x32_f16(Ar[1], B1, gr, 0,0,0);
      f4v gz = __builtin_amdgcn_mfma_f32_16x16x32_f16(Az[0], B0, z4, 0,0,0);
      gz     = __builtin_amdgcn_mfma_f32_16x16x32_f16(Az[1], B1, gz, 0,0,0);
      f4v gn = __builtin_amdgcn_mfma_f32_16x16x32_f16(An[0], B0, z4, 0,0,0);
      gn     = __builtin_amdgcn_mfma_f32_16x16x32_f16(An[1], B1, gn, 0,0,0);
      float xc = (float)((const _Float16*)xw)[c*130 + t];
      f4v hn;
      #pragma unroll
      for (int i = 0; i < 4; ++i) {
        float r  = fsig(fmaf(xc, wih0e[i], bb0e[i]) + gr[i]);
        float zf = fsig(fmaf(xc, wih1e[i], bb1e[i]) + gz[i]);
        float n  = ftanh(fmaf(xc, wih2e[i], bi2e[i]) + r*(gn[i] + bh2e[i]));
        float h  = fmaf(zf, hreg[i] - n, n);
        hreg[i] = h;
        hn[i] = h;
      }
      uint2 wv; wv.x = pk2(hn[0], hn[1]); wv.y = pk2(hn[2], hn[3]);
      *(uint2*)(He[(t+1)&1] + c*72 + m0) = wv;
    }
    WG_BARRIER_LDS();   // uniform across all 8 waves
  }
  // ---- epilogue: Eh/hw for t=127 from He[0] (= h_127); publish h_T ----
  if (w < 4) {
    const _Float16* Hc = He[0];
    half8 B0 = __builtin_bit_cast(half8, *(const uint4*)(Hc + c*72 + 8*q));
    half8 B1 = __builtin_bit_cast(half8, *(const uint4*)(Hc + c*72 + 32 + 8*q));
    if (w < 2) {
      f4v cu = __builtin_amdgcn_mfma_f32_16x16x32_f16(AX[0], B0, z4, 0,0,0);
      cu     = __builtin_amdgcn_mfma_f32_16x16x32_f16(AX[1], B1, cu, 0,0,0);
      unsigned* hpE = ehB + 127*17 + 8*w;
      float x0 = fexp2(fminf(cu[0], 15.5f));
      float x1 = fexp2(fminf(cu[1], 15.5f));
      float x2 = fexp2(fminf(cu[2], 15.5f));
      float x3 = fexp2(fminf(cu[3], 15.5f));
      hpE[2*q]   = pk2rne(x0, x1);
      hpE[2*q+1] = pk2rne(x2, x3);
    } else if (w == 2) {
      f4v cw = __builtin_amdgcn_mfma_f32_16x16x32_f16(AX[0], B0, z4, 0,0,0);
      cw     = __builtin_amdgcn_mfma_f32_16x16x32_f16(AX[1], B1, cw, 0,0,0);
      if (q == 0) ((float*)(ehB + 127*17))[16] = cw[0];
    }
    #pragma unroll
    for (int i = 0; i < 4; ++i)
      hTS[c*64 + m0 + i] = hreg[i];
  }
  WG_BARRIER_LDS();   // EhS + hTS complete and visible

  // ---- PHASE 2: decoder, all 8 waves, 2 elems/wave (R22 body) ----
  const int eA = 2*w, eB = eA + 1;
  const int a    = l & 31;
  const int half = l >> 5;
  unsigned* wbase = decScr + w*128;
  _Float16* ringA = (_Float16*)wbase;
  _Float16* ringB = (_Float16*)(wbase + 32);
  float*    dpA   = (float*)(wbase + 64);
  float*    dpB   = (float*)(wbase + 96);
  const float* hTA = hTS + eA*64;
  const float* hTB = hTS + eB*64;
  const unsigned* hprA0 = EhS + eA*2177 + l*17;
  const unsigned* hprA1 = EhS + eA*2177 + (64+l)*17;
  const unsigned* hprB0 = EhS + eB*2177 + l*17;
  const unsigned* hprB1 = EhS + eB*2177 + (64+l)*17;

  unsigned wr_r[32], wr_z[32], wr_n[32];
  {
    const f4v* wp = (const f4v*)W_hh_d;
    #pragma unroll
    for (int k = 0; k < 16; ++k) {
      f4v vr = wp[l*16 + k];
      f4v vz = wp[(64 + l)*16 + k];
      f4v vn = wp[(128 + l)*16 + k];
      wr_r[2*k] = pk2(vr.x, vr.y); wr_r[2*k+1] = pk2(vr.z, vr.w);
      wr_z[2*k] = pk2(vz.x, vz.y); wr_z[2*k+1] = pk2(vz.z, vz.w);
      wr_n[2*k] = pk2(vn.x, vn.y); wr_n[2*k+1] = pk2(vn.z, vn.w);
    }
  }
  float wih0 = W_ih_d[l], wih1 = W_ih_d[64+l], wih2 = W_ih_d[128+l];
  float bb0  = b_ih_d[l] + b_hh_d[l];
  float bb1  = b_ih_d[64+l] + b_hh_d[64+l];
  float bih2 = b_ih_d[128+l], bhh2 = b_hh_d[128+l];
  unsigned udr[16];
  {
    const f2* up = (const f2*)(W_d + a*64 + half*32);
    #pragma unroll
    for (int k = 0; k < 16; ++k) { f2 f = up[k]; udr[k] = pk2(f.x, f.y); }
  }
  float dprevA, dprevB;
  {
    const f4v* wi = (const f4v*)(W_init + l*64);
    const f4v* ga = (const f4v*)hTA;
    const f4v* gb = (const f4v*)hTB;
    f2 aa0={0,0}, aa1={0,0}, ba0={0,0}, ba1={0,0};
    #pragma unroll
    for (int k = 0; k < 16; ++k) {
      f4v wv = wi[k];
      f4v va = ga[k], vb = gb[k];
      aa0 = pkfma(wv.xy, va.xy, aa0);
      aa1 = pkfma(wv.zw, va.zw, aa1);
      ba0 = pkfma(wv.xy, vb.xy, ba0);
      ba1 = pkfma(wv.zw, vb.zw, ba1);
    }
    float bi = b_init[l];
    dprevA = bi + (aa0.x + aa0.y) + (aa1.x + aa1.y);
    dprevB = bi + (ba0.x + ba0.y) + (ba1.x + ba1.y);
  }
  float wout1 = W_out[l];
  float hw0A = __builtin_bit_cast(float, hprA0[16]);
  float hw1A = __builtin_bit_cast(float, hprA1[16]);
  float hw0B = __builtin_bit_cast(float, hprB0[16]);
  float hw1B = __builtin_bit_cast(float, hprB1[16]);
  float oprevA = y0[0], oprevB = y0[0];
  float bo = b_out[0];
  float c1;
  {
    float sv = v_d[a];
    sv += __shfl_xor(sv, 16); sv += __shfl_xor(sv, 8);
    sv += __shfl_xor(sv, 4);  sv += __shfl_xor(sv, 2); sv += __shfl_xor(sv, 1);
    c1 = LOG2E * sv;
  }
  ringA[l] = (_Float16)dprevA;
  ringB[l] = (_Float16)dprevB;

  #pragma unroll 1
  for (int s = 0; s < HOR; ++s) {
    float ar0A=0,ar1A=0,az0A=0,az1A=0,an0A=0,an1A=0;
    float ar0B=0,ar1B=0,az0B=0,az1B=0,an0B=0,an1B=0;
    gru_mv(ringA, wr_r, wr_z, wr_n, ar0A,ar1A,az0A,az1A,an0A,an1A);
    gru_mv(ringB, wr_r, wr_z, wr_n, ar0B,ar1B,az0B,az1B,an0B,an1B);
    float rA = fsig(fmaf(oprevA, wih0, bb0) + ar0A + ar1A);
    float zA = fsig(fmaf(oprevA, wih1, bb1) + az0A + az1A);
    float nA = ftanh(fmaf(oprevA, wih2, bih2) + rA * (an0A + an1A + bhh2));
    float dnewA = fmaf(zA, dprevA - nA, nA);
    float rB = fsig(fmaf(oprevB, wih0, bb0) + ar0B + ar1B);
    float zB = fsig(fmaf(oprevB, wih1, bb1) + az0B + az1B);
    float nB = ftanh(fmaf(oprevB, wih2, bih2) + rB * (an0B + an1B + bhh2));
    float dnewB = fmaf(zB, dprevB - nB, nB);
    dprevA = dnewA; dprevB = dnewB;
    ringA[l] = (_Float16)dnewA;
    ringB[l] = (_Float16)dnewB;
    {
      float accA = proj_dot(ringA + half*32, udr);
      float accB = proj_dot(ringB + half*32, udr);
      accA += __shfl_xor(accA, 32);
      accB += __shfl_xor(accB, 32);
      if (l < 32) {
        dpA[l] = fexp2(fminf(C2 * accA, 15.5f));
        dpB[l] = fexp2(fminf(C2 * accB, 15.5f));
      }
    }
    float rs0A = 0.f, rs1A = 0.f, rs0B = 0.f, rs1B = 0.f;
    #pragma unroll
    for (int j2 = 0; j2 < 8; ++j2) {
      f4v edA = *(const f4v*)&dpA[4*j2];
      f4v edB = *(const f4v*)&dpB[4*j2];
      half2_t haA0 = bch(hprA0[2*j2]), hbA0 = bch(hprA0[2*j2+1]);
      half2_t haA1 = bch(hprA1[2*j2]), hbA1 = bch(hprA1[2*j2+1]);
      half2_t haB0 = bch(hprB0[2*j2]), hbB0 = bch(hprB0[2*j2+1]);
      half2_t haB1 = bch(hprB1[2*j2]), hbB1 = bch(hprB1[2*j2+1]);
      float v0 = v_d[4*j2], v1 = v_d[4*j2+1], v2 = v_d[4*j2+2], v3 = v_d[4*j2+3];
      rs0A = grp4(rs0A, edA, haA0, hbA0, v0, v1, v2, v3);
      rs0B = grp4(rs0B, edB, haB0, hbB0, v0, v1, v2, v3);
      rs1A = grp4(rs1A, edA, haA1, hbA1, v0, v1, v2, v3);
      rs1B = grp4(rs1B, edB, haB1, hbB1, v0, v1, v2, v3);
    }
    float e0A = fexp2(fmaf(-C2, rs0A, c1));
    float e1A = fexp2(fmaf(-C2, rs1A, c1));
    float e0B = fexp2(fmaf(-C2, rs0B, c1));
    float e1B = fexp2(fmaf(-C2, rs1B, c1));
    float P0A = rdl63(wavesum_dpp(e0A + e1A));
    float P1A = rdl63(wavesum_dpp(fmaf(e0A, hw0A, e1A * hw1A)));
    float P2A = rdl63(wavesum_dpp(wout1 * dnewA));
    float P0B = rdl63(wavesum_dpp(e0B + e1B));
    float P1B = rdl63(wavesum_dpp(fmaf(e0B, hw0B, e1B * hw1B)));
    float P2B = rdl63(wavesum_dpp(wout1 * dnewB));
    float oA = fmaf(P1A, frcp(P0A), P2A + bo);
    float oB = fmaf(P1B, frcp(P0B), P2B + bo);
    if (l == 0) {
      out[(size_t)(e0 + eA) * HOR + s] = oA;
      out[(size_t)(e0 + eB) * HOR + s] = oB;
    }
    oprevA = oA; oprevB = oB;
  }
}

extern "C" void kernel_launch(void* const* d_in, const int* in_sizes, int n_in,
                              void* d_out, int out_size, void* d_ws, size_t ws_size,
                              hipStream_t stream) {
  const float* x      = (const float*)d_in[0];
  const float* W_ih_e = (const float*)d_in[1];
  const float* W_hh_e = (const float*)d_in[2];
  const float* b_ih_e = (const float*)d_in[3];
  const float* b_hh_e = (const float*)d_in[4];
  // d_in[5..8] = W_e, U_e, b_e, v_e : dead (softmax over size-1 axis == 1)
  const float* W_init = (const float*)d_in[9];
  const float* b_init = (const float*)d_in[10];
  const float* W_ih_d = (const float*)d_in[11];
  const float* W_hh_d = (const float*)d_in[12];
  const float* b_ih_d = (const float*)d_in[13];
  const float* b_hh_d = (const float*)d_in[14];
  const float* W_d    = (const float*)d_in[15];
  const float* U_d    = (const float*)d_in[16];
  const float* v_d    = (const float*)d_in[17];
  const float* W_out  = (const float*)d_in[18];
  const float* b_out  = (const float*)d_in[19];
  const float* y0     = (const float*)d_in[20];
  float* outp = (float*)d_out;

  darnn_fused<<<BATCH/16, 512, 0, stream>>>(x, W_ih_e, W_hh_e, b_ih_e, b_hh_e,
      U_d, W_out, W_init, b_init, W_ih_d, W_hh_d, b_ih_d, b_hh_d,
      W_d, v_d, b_out, y0, outp);
}

// Round 11
// 244.302 us; speedup vs baseline: 1.1555x; 1.0311x over previous
//
#include <hip/hip_runtime.h>
#include <math.h>

#define BATCH 4096
#define T 128
#define HOR 24

#define LOG2E 1.44269504088896f
#define C2    2.88539008177793f   // 2*log2(e)

typedef _Float16 half2_t __attribute__((ext_vector_type(2)));
typedef _Float16 half8   __attribute__((ext_vector_type(8)));
typedef float f2  __attribute__((ext_vector_type(2)));
typedef float f4v __attribute__((ext_vector_type(4)));

__device__ __forceinline__ float fexp2(float x){ return __builtin_amdgcn_exp2f(x); }
__device__ __forceinline__ float frcp(float x){ return __builtin_amdgcn_rcpf(x); }
__device__ __forceinline__ float fsig(float x){ return frcp(1.0f + fexp2(-LOG2E*x)); }
__device__ __forceinline__ float ftanh(float x){ return fmaf(-2.0f, frcp(1.0f + fexp2(C2*x)), 1.0f); }
__device__ __forceinline__ half2_t bch(unsigned u){ return __builtin_bit_cast(half2_t,u); }
__device__ __forceinline__ unsigned pk2(float a,float b){ return __builtin_bit_cast(unsigned, __builtin_amdgcn_cvt_pkrtz(a,b)); }
// RNE f32-pair -> packed f16 (for exp2 values: keep full fp16 accuracy, no RTZ bias)
__device__ __forceinline__ unsigned pk2rne(float a,float b){
  half2_t h; h.x = (_Float16)a; h.y = (_Float16)b;
  return __builtin_bit_cast(unsigned, h);
}
__device__ __forceinline__ float fdot2f(half2_t a, half2_t b, float c){
#if __has_builtin(__builtin_amdgcn_fdot2)
  return __builtin_amdgcn_fdot2(a,b,c,false);
#else
  return fmaf((float)a.x,(float)b.x, fmaf((float)a.y,(float)b.y,c));
#endif
}
__device__ __forceinline__ f2 pkfma(f2 a, f2 b, f2 c){ return __builtin_elementwise_fma(a,b,c); }

template <int CTRL, int RMASK>
__device__ __forceinline__ float dpp_add(float v) {
  int s = __builtin_amdgcn_update_dpp(0, __builtin_bit_cast(int, v), CTRL, RMASK, 0xf, true);
  return v + __builtin_bit_cast(float, s);
}
__device__ __forceinline__ float wavesum_dpp(float v) {
  v = dpp_add<0x111, 0xf>(v);
  v = dpp_add<0x112, 0xf>(v);
  v = dpp_add<0x114, 0xf>(v);
  v = dpp_add<0x118, 0xf>(v);
  v = dpp_add<0x142, 0xa>(v);
  v = dpp_add<0x143, 0xc>(v);
  return v;                     // total in lane 63
}
__device__ __forceinline__ float rdl63(float v){
  return __builtin_bit_cast(float, __builtin_amdgcn_readlane(__builtin_bit_cast(int, v), 63));
}

// Barrier that does NOT drain vmcnt: LDS producer/consumer ordering only.
#define WG_BARRIER_LDS() do {                                   \
    asm volatile("s_waitcnt lgkmcnt(0)" ::: "memory");          \
    __builtin_amdgcn_s_barrier();                               \
  } while (0)

__device__ __forceinline__ void gru_mv(const _Float16* hrow,
    const unsigned* wr_r, const unsigned* wr_z, const unsigned* wr_n,
    float& ar0, float& ar1, float& az0, float& az1, float& an0, float& an1)
{
  const uint4* hq = (const uint4*)hrow;
  #pragma unroll
  for (int q = 0; q < 8; ++q) {
    uint4 hv = hq[q];
    ar0 = fdot2f(bch(hv.x), bch(wr_r[4*q+0]), ar0);
    az0 = fdot2f(bch(hv.x), bch(wr_z[4*q+0]), az0);
    an0 = fdot2f(bch(hv.x), bch(wr_n[4*q+0]), an0);
    ar1 = fdot2f(bch(hv.y), bch(wr_r[4*q+1]), ar1);
    az1 = fdot2f(bch(hv.y), bch(wr_z[4*q+1]), az1);
    an1 = fdot2f(bch(hv.y), bch(wr_n[4*q+1]), an1);
    ar0 = fdot2f(bch(hv.z), bch(wr_r[4*q+2]), ar0);
    az0 = fdot2f(bch(hv.z), bch(wr_z[4*q+2]), az0);
    an0 = fdot2f(bch(hv.z), bch(wr_n[4*q+2]), an0);
    ar1 = fdot2f(bch(hv.w), bch(wr_r[4*q+3]), ar1);
    az1 = fdot2f(bch(hv.w), bch(wr_z[4*q+3]), az1);
    an1 = fdot2f(bch(hv.w), bch(wr_n[4*q+3]), an1);
  }
}

__device__ __forceinline__ float proj_dot(const _Float16* base, const unsigned* udr)
{
  float acc = 0.f;
  const uint4* hb = (const uint4*)base;
  #pragma unroll
  for (int q = 0; q < 4; ++q) {
    uint4 hv = hb[q];
    acc = fdot2f(bch(hv.x), bch(udr[4*q+0]), acc);
    acc = fdot2f(bch(hv.y), bch(udr[4*q+1]), acc);
    acc = fdot2f(bch(hv.z), bch(udr[4*q+2]), acc);
    acc = fdot2f(bch(hv.w), bch(udr[4*q+3]), acc);
  }
  return acc;
}

__device__ __forceinline__ half8 cvt8(f4v a, f4v b){
  half8 h;
  h[0]=(_Float16)a.x; h[1]=(_Float16)a.y; h[2]=(_Float16)a.z; h[3]=(_Float16)a.w;
  h[4]=(_Float16)b.x; h[5]=(_Float16)b.y; h[6]=(_Float16)b.z; h[7]=(_Float16)b.w;
  return h;
}

// 4-term grouped sigma-sum: returns acc + sum_k v_k / A_k with ONE rcp.
__device__ __forceinline__ float grp4(float acc, f4v ed,
                                      half2_t ha, half2_t hb,
                                      float v0, float v1, float v2, float v3)
{
  float a0 = fmaf(ed.x, (float)ha.x, 1.0f);
  float a1 = fmaf(ed.y, (float)ha.y, 1.0f);
  float a2 = fmaf(ed.z, (float)hb.x, 1.0f);
  float a3 = fmaf(ed.w, (float)hb.y, 1.0f);
  float d01 = a0 * a1;
  float d23 = a2 * a3;
  float n01 = fmaf(v0, a1, v1 * a0);
  float n23 = fmaf(v2, a3, v3 * a2);
  float nc  = fmaf(n01, d23, n23 * d01);
  return fmaf(nc, frcp(d01 * d23), acc);
}

// ============ FUSED kernel: enc (gate/Eh wave-split) + dec, Eh in LDS ======
// R25: R24's fusion removed the 35.6MB global seam (252 us, FETCH 18.3->1.7MB)
// but waves 4-7 idle through all 128 enc steps while gate waves 0-1 carry the
// Eh branch (2 MFMA + 4 exp2 + packs + 2 ds_write) IN SERIES with gates.
// Split: waves 0-3 = gates only; waves 4-5 = Eh (U_d rows 0-15/16-31); wave 6
// = hw. SIMD pairing (w, w+4) gives each SIMD a gate wave + an Eh wave
// concurrently -> R17's 2-contexts/SIMD with ZERO dead work. Race-free with
// the single barrier/step: Eh waves read He[t&1] (pre-barrier data), write
// EhS[t-1] (phase-2 only); gate waves write He[(t+1)&1]. Bit-identical math.
__global__ __launch_bounds__(512, 2)
void darnn_fused(const float* __restrict__ x,
                 const float* __restrict__ W_ih_e, const float* __restrict__ W_hh_e,
                 const float* __restrict__ b_ih_e, const float* __restrict__ b_hh_e,
                 const float* __restrict__ U_d, const float* __restrict__ W_out,
                 const float* __restrict__ W_init, const float* __restrict__ b_init,
                 const float* __restrict__ W_ih_d, const float* __restrict__ W_hh_d,
                 const float* __restrict__ b_ih_d, const float* __restrict__ b_hh_d,
                 const float* __restrict__ W_d, const float* __restrict__ v_d,
                 const float* __restrict__ b_out, const float* __restrict__ y0,
                 float* __restrict__ out)
{
  const int tid = threadIdx.x;
  const int w   = tid >> 6;      // 0..7
  const int l   = tid & 63;
  const int c   = l & 15;        // enc: MFMA column = element slot
  const int q   = l >> 4;        // quad
  const int e0  = blockIdx.x * 16;

  __shared__ __align__(16) unsigned EhS[16*2177];   // Eh fp16 pairs + hw f32, per elem
  __shared__ __align__(16) _Float16 He[2][16*72];   // ping-pong h[e][k], pad 72
  __shared__ __align__(16) unsigned xw[16*65];      // x fp16-pairs [e][65]
  __shared__ __align__(16) float    hTS[16*64];     // h_T per elem
  __shared__ __align__(16) unsigned decScr[8*128];  // per-wave dec scratch

  // ---- stage x + zero He[0] (cooperative, all 512 threads) ----
  for (int idx = tid; idx < 16*64; idx += 512) {
    int e = idx >> 6, j = idx & 63;
    f2 g = ((const f2*)(x + (size_t)(e0+e)*T))[j];
    xw[e*65 + j] = pk2(g.x, g.y);
  }
  for (int idx = tid; idx < 576; idx += 512) ((unsigned*)He[0])[idx] = 0;

  // ---- enc setup: gate waves (0-3) get W_hh A-frags + combine params;
  //      Eh waves (4-6) get U_d/W_out A-frags ----
  const int mw = w & 3;
  const int m0 = 16*mw + 4*q;
  half8 Ar[2], Az[2], An[2];
  f4v wih0e, wih1e, wih2e, bb0e, bb1e, bi2e, bh2e;
  half8 AX[2] = {{0,0,0,0,0,0,0,0},{0,0,0,0,0,0,0,0}};
  if (w < 4) {
    #pragma unroll
    for (int kap = 0; kap < 2; ++kap) {
      const f4v* pr = (const f4v*)(W_hh_e + (size_t)(16*mw + c)*64       + 32*kap + 8*q);
      const f4v* pz = (const f4v*)(W_hh_e + (size_t)(64 + 16*mw + c)*64  + 32*kap + 8*q);
      const f4v* pn = (const f4v*)(W_hh_e + (size_t)(128 + 16*mw + c)*64 + 32*kap + 8*q);
      Ar[kap] = cvt8(pr[0], pr[1]);
      Az[kap] = cvt8(pz[0], pz[1]);
      An[kap] = cvt8(pn[0], pn[1]);
    }
    wih0e = *(const f4v*)(W_ih_e + m0);
    wih1e = *(const f4v*)(W_ih_e + 64 + m0);
    wih2e = *(const f4v*)(W_ih_e + 128 + m0);
    bb0e  = *(const f4v*)(b_ih_e + m0)      + *(const f4v*)(b_hh_e + m0);
    bb1e  = *(const f4v*)(b_ih_e + 64 + m0) + *(const f4v*)(b_hh_e + 64 + m0);
    bi2e  = *(const f4v*)(b_ih_e + 128 + m0);
    bh2e  = *(const f4v*)(b_hh_e + 128 + m0);
  } else if (w < 6) {
    const int ew = w - 4;        // 0,1 -> U_d rows [16ew, 16ew+16)
    #pragma unroll
    for (int kap = 0; kap < 2; ++kap) {
      const f4v* p = (const f4v*)(U_d + (size_t)(16*ew + c)*64 + 32*kap + 8*q);
      AX[kap] = cvt8(p[0] * C2, p[1] * C2);
    }
  } else if (w == 6 && c == 0) {
    #pragma unroll
    for (int kap = 0; kap < 2; ++kap) {
      const f4v* p = (const f4v*)(W_out + 64 + 32*kap + 8*q);
      AX[kap] = cvt8(p[0], p[1]);
    }
  }
  f4v hreg = {0,0,0,0};
  const f4v z4 = {0,0,0,0};
  unsigned* ehB = EhS + c*2177;   // lane's elem row

  __syncthreads();

  // ---- PHASE 1: 128 enc steps; gates on waves 0-3, Eh/hw on waves 4-6 ----
  #pragma unroll 1
  for (int t = 0; t < T; ++t) {
    if (w < 4) {
      const _Float16* Hc = He[t & 1];
      half8 B0 = __builtin_bit_cast(half8, *(const uint4*)(Hc + c*72 + 8*q));
      half8 B1 = __builtin_bit_cast(half8, *(const uint4*)(Hc + c*72 + 32 + 8*q));
      f4v gr = __builtin_amdgcn_mfma_f32_16x16x32_f16(Ar[0], B0, z4, 0,0,0);
      gr     = __builtin_amdgcn_mfma_f32_16x16x32_f16(Ar[1], B1, gr, 0,0,0);
      f4v gz = __builtin_amdgcn_mfma_f32_16x16x32_f16(Az[0], B0, z4, 0,0,0);
      gz     = __builtin_amdgcn_mfma_f32_16x16x32_f16(Az[1], B1, gz, 0,0,0);
      f4v gn = __builtin_amdgcn_mfma_f32_16x16x32_f16(An[0], B0, z4, 0,0,0);
      gn     = __builtin_amdgcn_mfma_f32_16x16x32_f16(An[1], B1, gn, 0,0,0);
      float xc = (float)((const _Float16*)xw)[c*130 + t];
      f4v hn;
      #pragma unroll
      for (int i = 0; i < 4; ++i) {
        float r  = fsig(fmaf(xc, wih0e[i], bb0e[i]) + gr[i]);
        float zf = fsig(fmaf(xc, wih1e[i], bb1e[i]) + gz[i]);
        float n  = ftanh(fmaf(xc, wih2e[i], bi2e[i]) + r*(gn[i] + bh2e[i]));
        float h  = fmaf(zf, hreg[i] - n, n);
        hreg[i] = h;
        hn[i] = h;
      }
      uint2 wv; wv.x = pk2(hn[0], hn[1]); wv.y = pk2(hn[2], hn[3]);
      *(uint2*)(He[(t+1)&1] + c*72 + m0) = wv;
    } else if (w < 7 && t > 0) {
      // Eh/hw for h_{t-1} = He[t&1] (pre-barrier data), store slot t-1
      const _Float16* Hc = He[t & 1];
      half8 B0 = __builtin_bit_cast(half8, *(const uint4*)(Hc + c*72 + 8*q));
      half8 B1 = __builtin_bit_cast(half8, *(const uint4*)(Hc + c*72 + 32 + 8*q));
      f4v cu = __builtin_amdgcn_mfma_f32_16x16x32_f16(AX[0], B0, z4, 0,0,0);
      cu     = __builtin_amdgcn_mfma_f32_16x16x32_f16(AX[1], B1, cu, 0,0,0);
      if (w < 6) {
        unsigned* hpE = ehB + (t-1)*17 + 8*(w-4);
        float x0 = fexp2(fminf(cu[0], 15.5f));
        float x1 = fexp2(fminf(cu[1], 15.5f));
        float x2 = fexp2(fminf(cu[2], 15.5f));
        float x3 = fexp2(fminf(cu[3], 15.5f));
        hpE[2*q]   = pk2rne(x0, x1);
        hpE[2*q+1] = pk2rne(x2, x3);
      } else if (q == 0) {
        ((float*)(ehB + (t-1)*17))[16] = cu[0];
      }
    }
    WG_BARRIER_LDS();   // uniform across all 8 waves
  }
  // ---- epilogue: Eh/hw for t=127 from He[0] (= h_127); gate waves -> hTS ----
  if (w < 4) {
    #pragma unroll
    for (int i = 0; i < 4; ++i)
      hTS[c*64 + m0 + i] = hreg[i];
  } else if (w < 7) {
    const _Float16* Hc = He[0];
    half8 B0 = __builtin_bit_cast(half8, *(const uint4*)(Hc + c*72 + 8*q));
    half8 B1 = __builtin_bit_cast(half8, *(const uint4*)(Hc + c*72 + 32 + 8*q));
    f4v cu = __builtin_amdgcn_mfma_f32_16x16x32_f16(AX[0], B0, z4, 0,0,0);
    cu     = __builtin_amdgcn_mfma_f32_16x16x32_f16(AX[1], B1, cu, 0,0,0);
    if (w < 6) {
      unsigned* hpE = ehB + 127*17 + 8*(w-4);
      float x0 = fexp2(fminf(cu[0], 15.5f));
      float x1 = fexp2(fminf(cu[1], 15.5f));
      float x2 = fexp2(fminf(cu[2], 15.5f));
      float x3 = fexp2(fminf(cu[3], 15.5f));
      hpE[2*q]   = pk2rne(x0, x1);
      hpE[2*q+1] = pk2rne(x2, x3);
    } else if (q == 0) {
      ((float*)(ehB + 127*17))[16] = cu[0];
    }
  }
  WG_BARRIER_LDS();   // EhS + hTS complete and visible

  // ---- PHASE 2: decoder, all 8 waves, 2 elems/wave (R22 body) ----
  const int eA = 2*w, eB = eA + 1;
  const int a    = l & 31;
  const int half = l >> 5;
  unsigned* wbase = decScr + w*128;
  _Float16* ringA = (_Float16*)wbase;
  _Float16* ringB = (_Float16*)(wbase + 32);
  float*    dpA   = (float*)(wbase + 64);
  float*    dpB   = (float*)(wbase + 96);
  const float* hTA = hTS + eA*64;
  const float* hTB = hTS + eB*64;
  const unsigned* hprA0 = EhS + eA*2177 + l*17;
  const unsigned* hprA1 = EhS + eA*2177 + (64+l)*17;
  const unsigned* hprB0 = EhS + eB*2177 + l*17;
  const unsigned* hprB1 = EhS + eB*2177 + (64+l)*17;

  unsigned wr_r[32], wr_z[32], wr_n[32];
  {
    const f4v* wp = (const f4v*)W_hh_d;
    #pragma unroll
    for (int k = 0; k < 16; ++k) {
      f4v vr = wp[l*16 + k];
      f4v vz = wp[(64 + l)*16 + k];
      f4v vn = wp[(128 + l)*16 + k];
      wr_r[2*k] = pk2(vr.x, vr.y); wr_r[2*k+1] = pk2(vr.z, vr.w);
      wr_z[2*k] = pk2(vz.x, vz.y); wr_z[2*k+1] = pk2(vz.z, vz.w);
      wr_n[2*k] = pk2(vn.x, vn.y); wr_n[2*k+1] = pk2(vn.z, vn.w);
    }
  }
  float wih0 = W_ih_d[l], wih1 = W_ih_d[64+l], wih2 = W_ih_d[128+l];
  float bb0  = b_ih_d[l] + b_hh_d[l];
  float bb1  = b_ih_d[64+l] + b_hh_d[64+l];
  float bih2 = b_ih_d[128+l], bhh2 = b_hh_d[128+l];
  unsigned udr[16];
  {
    const f2* up = (const f2*)(W_d + a*64 + half*32);
    #pragma unroll
    for (int k = 0; k < 16; ++k) { f2 f = up[k]; udr[k] = pk2(f.x, f.y); }
  }
  float dprevA, dprevB;
  {
    const f4v* wi = (const f4v*)(W_init + l*64);
    const f4v* ga = (const f4v*)hTA;
    const f4v* gb = (const f4v*)hTB;
    f2 aa0={0,0}, aa1={0,0}, ba0={0,0}, ba1={0,0};
    #pragma unroll
    for (int k = 0; k < 16; ++k) {
      f4v wv = wi[k];
      f4v va = ga[k], vb = gb[k];
      aa0 = pkfma(wv.xy, va.xy, aa0);
      aa1 = pkfma(wv.zw, va.zw, aa1);
      ba0 = pkfma(wv.xy, vb.xy, ba0);
      ba1 = pkfma(wv.zw, vb.zw, ba1);
    }
    float bi = b_init[l];
    dprevA = bi + (aa0.x + aa0.y) + (aa1.x + aa1.y);
    dprevB = bi + (ba0.x + ba0.y) + (ba1.x + ba1.y);
  }
  float wout1 = W_out[l];
  float hw0A = __builtin_bit_cast(float, hprA0[16]);
  float hw1A = __builtin_bit_cast(float, hprA1[16]);
  float hw0B = __builtin_bit_cast(float, hprB0[16]);
  float hw1B = __builtin_bit_cast(float, hprB1[16]);
  float oprevA = y0[0], oprevB = y0[0];
  float bo = b_out[0];
  float c1;
  {
    float sv = v_d[a];
    sv += __shfl_xor(sv, 16); sv += __shfl_xor(sv, 8);
    sv += __shfl_xor(sv, 4);  sv += __shfl_xor(sv, 2); sv += __shfl_xor(sv, 1);
    c1 = LOG2E * sv;
  }
  ringA[l] = (_Float16)dprevA;
  ringB[l] = (_Float16)dprevB;

  #pragma unroll 1
  for (int s = 0; s < HOR; ++s) {
    float ar0A=0,ar1A=0,az0A=0,az1A=0,an0A=0,an1A=0;
    float ar0B=0,ar1B=0,az0B=0,az1B=0,an0B=0,an1B=0;
    gru_mv(ringA, wr_r, wr_z, wr_n, ar0A,ar1A,az0A,az1A,an0A,an1A);
    gru_mv(ringB, wr_r, wr_z, wr_n, ar0B,ar1B,az0B,az1B,an0B,an1B);
    float rA = fsig(fmaf(oprevA, wih0, bb0) + ar0A + ar1A);
    float zA = fsig(fmaf(oprevA, wih1, bb1) + az0A + az1A);
    float nA = ftanh(fmaf(oprevA, wih2, bih2) + rA * (an0A + an1A + bhh2));
    float dnewA = fmaf(zA, dprevA - nA, nA);
    float rB = fsig(fmaf(oprevB, wih0, bb0) + ar0B + ar1B);
    float zB = fsig(fmaf(oprevB, wih1, bb1) + az0B + az1B);
    float nB = ftanh(fmaf(oprevB, wih2, bih2) + rB * (an0B + an1B + bhh2));
    float dnewB = fmaf(zB, dprevB - nB, nB);
    dprevA = dnewA; dprevB = dnewB;
    ringA[l] = (_Float16)dnewA;
    ringB[l] = (_Float16)dnewB;
    {
      float accA = proj_dot(ringA + half*32, udr);
      float accB = proj_dot(ringB + half*32, udr);
      accA += __shfl_xor(accA, 32);
      accB += __shfl_xor(accB, 32);
      if (l < 32) {
        dpA[l] = fexp2(fminf(C2 * accA, 15.5f));
        dpB[l] = fexp2(fminf(C2 * accB, 15.5f));
      }
    }
    float rs0A = 0.f, rs1A = 0.f, rs0B = 0.f, rs1B = 0.f;
    #pragma unroll
    for (int j2 = 0; j2 < 8; ++j2) {
      f4v edA = *(const f4v*)&dpA[4*j2];
      f4v edB = *(const f4v*)&dpB[4*j2];
      half2_t haA0 = bch(hprA0[2*j2]), hbA0 = bch(hprA0[2*j2+1]);
      half2_t haA1 = bch(hprA1[2*j2]), hbA1 = bch(hprA1[2*j2+1]);
      half2_t haB0 = bch(hprB0[2*j2]), hbB0 = bch(hprB0[2*j2+1]);
      half2_t haB1 = bch(hprB1[2*j2]), hbB1 = bch(hprB1[2*j2+1]);
      float v0 = v_d[4*j2], v1 = v_d[4*j2+1], v2 = v_d[4*j2+2], v3 = v_d[4*j2+3];
      rs0A = grp4(rs0A, edA, haA0, hbA0, v0, v1, v2, v3);
      rs0B = grp4(rs0B, edB, haB0, hbB0, v0, v1, v2, v3);
      rs1A = grp4(rs1A, edA, haA1, hbA1, v0, v1, v2, v3);
      rs1B = grp4(rs1B, edB, haB1, hbB1, v0, v1, v2, v3);
    }
    float e0A = fexp2(fmaf(-C2, rs0A, c1));
    float e1A = fexp2(fmaf(-C2, rs1A, c1));
    float e0B = fexp2(fmaf(-C2, rs0B, c1));
    float e1B = fexp2(fmaf(-C2, rs1B, c1));
    float P0A = rdl63(wavesum_dpp(e0A + e1A));
    float P1A = rdl63(wavesum_dpp(fmaf(e0A, hw0A, e1A * hw1A)));
    float P2A = rdl63(wavesum_dpp(wout1 * dnewA));
    float P0B = rdl63(wavesum_dpp(e0B + e1B));
    float P1B = rdl63(wavesum_dpp(fmaf(e0B, hw0B, e1B * hw1B)));
    float P2B = rdl63(wavesum_dpp(wout1 * dnewB));
    float oA = fmaf(P1A, frcp(P0A), P2A + bo);
    float oB = fmaf(P1B, frcp(P0B), P2B + bo);
    if (l == 0) {
      out[(size_t)(e0 + eA) * HOR + s] = oA;
      out[(size_t)(e0 + eB) * HOR + s] = oB;
    }
    oprevA = oA; oprevB = oB;
  }
}

extern "C" void kernel_launch(void* const* d_in, const int* in_sizes, int n_in,
                              void* d_out, int out_size, void* d_ws, size_t ws_size,
                              hipStream_t stream) {
  const float* x      = (const float*)d_in[0];
  const float* W_ih_e = (const float*)d_in[1];
  const float* W_hh_e = (const float*)d_in[2];
  const float* b_ih_e = (const float*)d_in[3];
  const float* b_hh_e = (const float*)d_in[4];
  // d_in[5..8] = W_e, U_e, b_e, v_e : dead (softmax over size-1 axis == 1)
  const float* W_init = (const float*)d_in[9];
  const float* b_init = (const float*)d_in[10];
  const float* W_ih_d = (const float*)d_in[11];
  const float* W_hh_d = (const float*)d_in[12];
  const float* b_ih_d = (const float*)d_in[13];
  const float* b_hh_d = (const float*)d_in[14];
  const float* W_d    = (const float*)d_in[15];
  const float* U_d    = (const float*)d_in[16];
  const float* v_d    = (const float*)d_in[17];
  const float* W_out  = (const float*)d_in[18];
  const float* b_out  = (const float*)d_in[19];
  const float* y0     = (const float*)d_in[20];
  float* outp = (float*)d_out;

  darnn_fused<<<BATCH/16, 512, 0, stream>>>(x, W_ih_e, W_hh_e, b_ih_e, b_hh_e,
      U_d, W_out, W_init, b_init, W_ih_d, W_hh_d, b_ih_d, b_hh_d,
      W_d, v_d, b_out, y0, outp);
}